// Round 6
// baseline (271.143 us; speedup 1.0000x reference)
//
#include <hip/hip_runtime.h>
#include <cstdint>
#include <cstddef>

typedef __bf16 bf16x8 __attribute__((ext_vector_type(8)));
typedef __bf16 bf16x4 __attribute__((ext_vector_type(4)));
typedef short s16x4 __attribute__((ext_vector_type(4)));
typedef float f32x4 __attribute__((ext_vector_type(4)));

__device__ __forceinline__ ushort f2bf(float f) {
  union { float f; uint32_t u; } v; v.f = f;
  uint32_t r = (v.u + 0x7fffu + ((v.u >> 16) & 1u)) >> 16;
  return (ushort)r;
}

__device__ __forceinline__ float fast_exp2(float x) {
#if defined(__HIP_DEVICE_COMPILE__) && __has_builtin(__builtin_amdgcn_exp2f)
  return __builtin_amdgcn_exp2f(x);
#else
  return exp2f(x);
#endif
}

// K=16 bf16 MFMA (C-layout of a 16x16 result feeds directly as B operand).
__device__ __forceinline__ f32x4 mfma16(bf16x4 a, bf16x4 b, f32x4 c) {
#if defined(__HIP_DEVICE_COMPILE__)
#if __has_builtin(__builtin_amdgcn_mfma_f32_16x16x16_bf16)
  return __builtin_amdgcn_mfma_f32_16x16x16_bf16(a, b, c, 0, 0, 0);
#else
  return __builtin_amdgcn_mfma_f32_16x16x16bf16_1k(
      __builtin_bit_cast(s16x4, a), __builtin_bit_cast(s16x4, b), c, 0, 0, 0);
#endif
#else
  (void)a; (void)b;
  return c;  // host stub, never executed
#endif
}

__device__ __forceinline__ void glds16(const ushort* g, ushort* l) {
  __builtin_amdgcn_global_load_lds((const __attribute__((address_space(1))) void*)g,
                                   (__attribute__((address_space(3))) void*)l, 16, 0, 0);
}

// ---------------- fused weight transposes: fp32 [R][C] -> bf16 [C][R] ----------------
// blockIdx.x < 96: Wqkv (1024x3072); else: Wo (1024x1024)
__global__ void prep_weights(const float* __restrict__ Wqkv, const float* __restrict__ Wo,
                             ushort* __restrict__ Wqkv_t, ushort* __restrict__ Wo_t) {
  __shared__ ushort t[32][33];
  const int bx = blockIdx.x;
  const float* in;
  ushort* out;
  int C, c0;
  if (bx < 96) { in = Wqkv; out = Wqkv_t; C = 3072; c0 = bx * 32; }
  else         { in = Wo;   out = Wo_t;   C = 1024; c0 = (bx - 96) * 32; }
  const int R = 1024;
  const int r0 = blockIdx.y * 32;
  const int tx = threadIdx.x, ty = threadIdx.y;  // 32 x 8
#pragma unroll
  for (int i = 0; i < 4; ++i)
    t[ty + i * 8][tx] = f2bf(in[(size_t)(r0 + ty + i * 8) * C + c0 + tx]);
  __syncthreads();
#pragma unroll
  for (int i = 0; i < 4; ++i)
    out[(size_t)(c0 + ty + i * 8) * R + r0 + tx] = t[tx][ty + i * 8];
}

// =====================================================================
// Triple-buffered bf16 GEMM, 128x128 tile, BK=32, 4 waves of 64x64
// (acc = 64 regs; proven spill-free at 3 waves/SIMD). LDS 48 KiB ->
// 3 blocks/CU; grids are exact multiples of 256-CU residency.
//
// MODE 0 (QKV projection): A comes DIRECTLY from x (fp32) -- the
//   former conv_bf16 dispatch is folded into staging. A is
//   register-staged (T14 split): 4x float4 loads for tile t+2 issue
//   BEFORE the MFMA cluster; vmcnt(2) + cvt->bf16 + 2x ds_write_b128
//   (at the permuted slot) after it -- latency hides under compute.
//   B stays global_load_lds DMA (permuted source, linear dest).
//   Per-iter waits: vmcnt(2) leaves only this iter's 2 B-DMAs in
//   flight; lgkmcnt(0) publishes the ds_writes before the barrier.
// MODE 1 (output projection): R4's pure-DMA path (stage A+B, VMC4).
//
// Shared: slot permutation slot(r,q) = r*4 + ((q+(r>>1))&3) within
// 16-row x 4-chunk(16B) sub-blocks (conflict-free ds_read_b128,
// HW-verified R2-R4); one raw barrier + counted vmcnt per K-step;
// setprio around the 16-MFMA cluster; XCD-aware bijective remap.
// MODE 0 epilogue: scatter to Q (scaled 0.125*log2e) / K / V^T tiled,
// 2 per-64-col-chunk LDS-staged passes (R4-verified).
// =====================================================================
#define BAR8() do { asm volatile("" ::: "memory"); \
                    __builtin_amdgcn_s_barrier();  \
                    asm volatile("" ::: "memory"); } while (0)
#define VMC4()  asm volatile("s_waitcnt vmcnt(4)" ::: "memory")
#define VMC2()  asm volatile("s_waitcnt vmcnt(2)" ::: "memory")
#define VMC0()  asm volatile("s_waitcnt vmcnt(0)" ::: "memory")
#define LGKM0() asm volatile("s_waitcnt lgkmcnt(0)" ::: "memory")

template <int MODE>
__launch_bounds__(256, 3)
__global__ void gemm_tb(const ushort* __restrict__ A, const float* __restrict__ Af,
                        const ushort* __restrict__ Bt, const float* __restrict__ bias,
                        ushort* __restrict__ o0, ushort* __restrict__ o1,
                        ushort* __restrict__ o2, float* __restrict__ of,
                        int M, int N, int K) {
  __shared__ ushort smem[24576];  // 48 KiB: A bufs [0,12288), B bufs [12288,24576)
  const int NT = K >> 5;
  const int tid = threadIdx.x;
  const int wid = tid >> 6;
  const int lane = tid & 63;
  const int quad = lane >> 4;
  const int l16 = lane & 15;
  const int wm = (wid >> 1) * 64;
  const int wn = (wid & 1) * 64;

  // XCD-aware bijective remap (gridDim.x*gridDim.y % 8 == 0 in both modes)
  int wg = blockIdx.y * gridDim.x + blockIdx.x;
  const int ntx = gridDim.x;
  const int cpx = (ntx * gridDim.y) >> 3;
  wg = (wg & 7) * cpx + (wg >> 3);
  const int m0 = (wg / ntx) * 128;
  const int n0 = (wg % ntx) * 128;

  // ---- staging addressing ----
  const int r_l = lane >> 2;                      // row within 16-row sub-block
  const int q_n = lane & 3;                       // natural k-chunk (MODE 0 A-loads)
  const int q_l = ((lane & 3) - (r_l >> 1)) & 3;  // permuted source chunk (DMA paths)
  // MODE 0: A fp32 source at natural position; write lands at permuted slot.
  const float* gAf = Af + (size_t)(m0 + wid * 32 + r_l) * K + q_n * 8;
  const int aslot = r_l * 4 + ((q_n + (r_l >> 1)) & 3);
  ushort* dAw = smem + wid * 1024 + aslot * 8;    // + u*512 + bs*4096
  // MODE 1: A bf16 DMA (permuted source, linear dest)
  const ushort* gA0 = A + (size_t)(m0 + wid * 32 + r_l) * K + q_l * 8;
  ushort* dA0 = smem + wid * 1024 + lane * 8;
  // B DMA (both modes)
  const ushort* gB0 = Bt + (size_t)(n0 + wid * 32 + r_l) * K + q_l * 8;
  ushort* dB0 = smem + 12288 + wid * 1024 + lane * 8;

  float4 af4[2][2];
  auto issueA = [&](int t) {  // 4 float4 loads (A tile t, this thread's 16 f32)
    const float* s0 = gAf + t * 32;
#pragma unroll
    for (int u = 0; u < 2; ++u) {
      af4[u][0] = *(const float4*)(s0 + u * 16 * K);
      af4[u][1] = *(const float4*)(s0 + u * 16 * K + 4);
    }
  };
  auto cvtWriteA = [&](int bs) {  // 16 cvt + 2 ds_write_b128 at permuted slots
#pragma unroll
    for (int u = 0; u < 2; ++u) {
      bf16x8 w;
      w[0] = (__bf16)af4[u][0].x; w[1] = (__bf16)af4[u][0].y;
      w[2] = (__bf16)af4[u][0].z; w[3] = (__bf16)af4[u][0].w;
      w[4] = (__bf16)af4[u][1].x; w[5] = (__bf16)af4[u][1].y;
      w[6] = (__bf16)af4[u][1].z; w[7] = (__bf16)af4[u][1].w;
      *(bf16x8*)(dAw + bs * 4096 + u * 512) = w;
    }
  };
  auto stageB = [&](int t, int bs) {  // 2 glds16
    const ushort* sb = gB0 + t * 32;
    ushort* db = dB0 + bs * 4096;
    glds16(sb, db);
    glds16(sb + 16 * K, db + 512);
  };
  auto stageAB = [&](int t, int bs) {  // MODE 1: 4 glds16
    const ushort* sa = gA0 + t * 32;
    ushort* da = dA0 + bs * 4096;
    glds16(sa, da);
    glds16(sa + 16 * K, da + 512);
    stageB(t, bs);
  };

  // ---- fragment read addressing ----
  const int slot8 = (l16 * 4 + ((quad + (l16 >> 1)) & 3)) * 8;
  const int abase = (wm >> 4) * 512 + slot8;            // + b*4096
  const int bbase = 12288 + (wn >> 4) * 512 + slot8;    // + b*4096

  f32x4 acc[4][4];
#pragma unroll
  for (int i = 0; i < 4; ++i)
#pragma unroll
    for (int j = 0; j < 4; ++j) acc[i][j] = (f32x4){0.f, 0.f, 0.f, 0.f};

  // ---- prologue: 2-deep prefetch ----
  if constexpr (MODE == 0) {
    issueA(0); stageB(0, 0);
    VMC0();             // A0 loads + B0 DMA complete
    cvtWriteA(0);
    issueA(1); stageB(1, 1);
    VMC2();             // A1 loads done; B1 DMA may stay in flight
    cvtWriteA(1);
    LGKM0();            // publish ds_writes
  } else {
    stageAB(0, 0);
    stageAB(1, 1);
    VMC4();             // tile 0 landed; tile 1 may stay in flight
  }
  BAR8();

  int b = 0;
  for (int t = 0; t < NT; ++t) {
    bf16x8 af[4], bfr[4];
    const int boff = b * 4096;
#pragma unroll
    for (int i = 0; i < 4; ++i)
      af[i] = *(const bf16x8*)(smem + boff + abase + i * 512);
#pragma unroll
    for (int j = 0; j < 4; ++j)
      bfr[j] = *(const bf16x8*)(smem + boff + bbase + j * 512);
    const int b2 = (b == 0) ? 2 : b - 1;    // (t+2) % 3
    if constexpr (MODE == 0) {
      if (t + 2 < NT) { issueA(t + 2); stageB(t + 2, b2); }
    } else {
      if (t + 2 < NT) stageAB(t + 2, b2);
    }
    __builtin_amdgcn_s_setprio(1);
#pragma unroll
    for (int i = 0; i < 4; ++i)
#pragma unroll
      for (int j = 0; j < 4; ++j)
        acc[i][j] = __builtin_amdgcn_mfma_f32_16x16x32_bf16(af[i], bfr[j], acc[i][j], 0, 0, 0);
    __builtin_amdgcn_s_setprio(0);
    if constexpr (MODE == 0) {
      // vmcnt(2): this iter's A-loads complete (and B(t+1) from last iter);
      // only this iter's 2 B-DMAs stay in flight. Then convert+write A(t+2).
      if (t + 2 < NT) { VMC2(); cvtWriteA(b2); LGKM0(); }
      else if (t + 1 < NT) { VMC0(); }
    } else {
      if (t + 2 < NT) { VMC4(); } else if (t + 1 < NT) { VMC0(); }
    }
    BAR8();
    b = (b == 2) ? 0 : b + 1;
  }

  if (MODE == 1) {
#pragma unroll
    for (int i = 0; i < 4; ++i)
#pragma unroll
      for (int j = 0; j < 4; ++j) {
        const int col = n0 + wn + j * 16 + l16;
        const float bv = bias[col];
#pragma unroll
        for (int r = 0; r < 4; ++r) {
          const int row = m0 + wm + i * 16 + quad * 4 + r;
          of[(size_t)row * N + col] = acc[i][j][r] + bv;
        }
      }
  } else {
    // ---- scatter epilogue: 2 per-64-col-chunk passes, staged in LDS ----
    const int bb = m0 >> 11;
    const int s0 = m0 & 2047;
    const int wr = wid >> 1;     // row-half owner (R base = wr*64)
    const int wcol = wid & 1;    // col-half owner
#pragma unroll
    for (int hc = 0; hc < 2; ++hc) {
      const int gc0 = n0 + hc * 64;
      const int sel = gc0 >> 10;              // 0=Q 1=K 2=V (chunk head-aligned)
      const int head = (gc0 & 1023) >> 6;
      const size_t bh = (size_t)(bb * 16 + head);
      __syncthreads();                        // K-loop / prior pass reads done
      if (wcol == hc) {
#pragma unroll
        for (int j = 0; j < 4; ++j) {
          const int dloc = j * 16 + l16;      // 0..63
          const float bv = bias[gc0 + dloc];
#pragma unroll
          for (int i = 0; i < 4; ++i) {
#pragma unroll
            for (int r = 0; r < 4; ++r) {
              const int R = wr * 64 + i * 16 + quad * 4 + r;   // 0..127
              float v = acc[i][j][r] + bv;
              if (sel == 0) v *= 0.18033688011112042f;  // (1/8)*log2(e)
              const ushort u = f2bf(v);
              if (sel == 2) {
                const int lc = R >> 3;        // s-chunk 0..15
                smem[dloc * 128 + ((lc ^ (dloc & 7)) << 3) + (R & 7)] = u;
              } else {
                smem[R * 64 + (((dloc >> 3) ^ (R & 7)) << 3) + (dloc & 7)] = u;
              }
            }
          }
        }
      }
      __syncthreads();
      if (sel != 2) {
        ushort* o = sel ? o1 : o0;
        const int R = tid >> 1;               // 0..127
        const int gh = tid & 1;               // 64B half of the row
        ushort* dst = o + (bh * 2048 + s0 + R) * 64 + gh * 32;
        const int key = R & 7;
        const uint4* srow = (const uint4*)(smem + R * 64);
#pragma unroll
        for (int g = 0; g < 4; ++g)
          ((uint4*)dst)[g] = srow[(gh * 4 + g) ^ key];
      } else {
        const int d = tid >> 2;               // 0..63
        const int sq = tid & 3;               // 32-s quarter
        ushort* dst = o2 + (((size_t)(bh * 32 + (s0 >> 6) + (sq >> 1))) << 12) +
                      d * 64 + (sq & 1) * 32;
        const uint4* srow = (const uint4*)(smem + d * 128);
#pragma unroll
        for (int g = 0; g < 4; ++g)
          ((uint4*)dst)[g] = srow[(sq * 4 + g) ^ (d & 7)];
      }
    }
  }
}

// ---------------- flash attention (causal) ----------------
// setprio around MFMA clusters; XCD remap: all 8 pair-blocks of one (b,h)
// on one XCD (8 bh x 512KB K/V = one 4MB L2).
__launch_bounds__(256)
__global__ void attn_fused(const ushort* __restrict__ Qb, const ushort* __restrict__ Kb,
                           const ushort* __restrict__ Vt, ushort* __restrict__ Ob) {
  int wg0 = blockIdx.y * 8 + blockIdx.x;
  const int w = (wg0 & 7) * 64 + (wg0 >> 3);  // bijective over 512
  const int bh = w >> 3;           // b*16 + h
  const int pair = w & 7;          // 0..7
  const int tid = threadIdx.x;
  const int wid = tid >> 6;
  const int lane = tid & 63;
  const int quad = lane >> 4;
  const int l16 = lane & 15;

  __shared__ ushort Ks[2][2][64 * 32];
  __shared__ ushort Vs[2][2][64 * 32];

  const int lr = lane >> 2;
  const int jphys = lane & 3;
  const int skey = (lr >> 1) & 3;
  const int jlog = jphys ^ skey;
  const int srow = wid * 16 + lr;
  const ushort* KgL = Kb + (size_t)bh * 2048 * 64 + (size_t)srow * 64 + jlog * 8;
  const ushort* VgL = Vt + (size_t)bh * 32 * 4096 + (size_t)srow * 64 + jlog * 8;
  ushort* ldsK0[2], *ldsK1[2], *ldsV0[2], *ldsV1[2];
#pragma unroll
  for (int buf = 0; buf < 2; ++buf) {
    ldsK0[buf] = &Ks[buf][0][wid * 16 * 32] + lane * 8;
    ldsK1[buf] = &Ks[buf][1][wid * 16 * 32] + lane * 8;
    ldsV0[buf] = &Vs[buf][0][wid * 16 * 32] + lane * 8;
    ldsV1[buf] = &Vs[buf][1][wid * 16 * 32] + lane * 8;
  }
  auto stage = [&](int jt) {
    const int buf = jt & 1;
    const ushort* ks = KgL + (size_t)jt * 4096;
    const ushort* vs = VgL + (size_t)jt * 4096;
    glds16(ks, ldsK0[buf]);
    glds16(ks + 32, ldsK1[buf]);
    glds16(vs, ldsV0[buf]);
    glds16(vs + 32, ldsV1[buf]);
  };

  const int rkey = (l16 >> 1) & 3;
  const int b = bh >> 4, h = bh & 15;

  auto process = [&](int qt) {
    const int qg0 = qt * 128 + wid * 32;

    const ushort* Qg = Qb + ((size_t)bh * 2048 + qg0) * 64;
    bf16x8 qa[2][2];
#pragma unroll
    for (int f = 0; f < 2; ++f)
#pragma unroll
      for (int hh = 0; hh < 2; ++hh)
        qa[f][hh] = *(const bf16x8*)(Qg + (f * 16 + l16) * 64 + hh * 32 + quad * 8);

    f32x4 o[2][4];
    float rs[2];
#pragma unroll
    for (int f = 0; f < 2; ++f) {
      rs[f] = 0.f;
#pragma unroll
      for (int m = 0; m < 4; ++m) o[f][m] = (f32x4){0.f, 0.f, 0.f, 0.f};
    }

    const int nIt = 2 * qt + 2;
    stage(0);

    for (int jt = 0; jt < nIt; ++jt) {
      __syncthreads();
      if (jt + 1 < nIt) stage(jt + 1);

      const int kvb = jt * 64;
      if (kvb > qg0 + 31) continue;
      const int buf = jt & 1;

      f32x4 s[2][4];
      __builtin_amdgcn_s_setprio(1);
#pragma unroll
      for (int n = 0; n < 4; ++n) {
        const int koff = (n * 16 + l16) * 32 + (quad ^ rkey) * 8;
        bf16x8 kb0 = *(const bf16x8*)&Ks[buf][0][koff];
        bf16x8 kb1 = *(const bf16x8*)&Ks[buf][1][koff];
#pragma unroll
        for (int f = 0; f < 2; ++f) {
          f32x4 z = (f32x4){0.f, 0.f, 0.f, 0.f};
          z = __builtin_amdgcn_mfma_f32_16x16x32_bf16(kb0, qa[f][0], z, 0, 0, 0);
          z = __builtin_amdgcn_mfma_f32_16x16x32_bf16(kb1, qa[f][1], z, 0, 0, 0);
          s[f][n] = z;
        }
      }
      __builtin_amdgcn_s_setprio(0);

      bf16x4 p[2][4];
      if (kvb + 63 <= qg0) {
#pragma unroll
        for (int f = 0; f < 2; ++f)
#pragma unroll
          for (int n = 0; n < 4; ++n) {
            float pe[4];
#pragma unroll
            for (int r = 0; r < 4; ++r) {
              pe[r] = fast_exp2(s[f][n][r]);
              rs[f] += pe[r];
            }
            p[f][n] = (bf16x4){(__bf16)pe[0], (__bf16)pe[1], (__bf16)pe[2], (__bf16)pe[3]};
          }
      } else {
#pragma unroll
        for (int f = 0; f < 2; ++f) {
          const int qg = qg0 + f * 16 + l16;
#pragma unroll
          for (int n = 0; n < 4; ++n) {
            const int kg0 = kvb + n * 16 + quad * 4;
            float pe[4];
#pragma unroll
            for (int r = 0; r < 4; ++r) {
              float e = fast_exp2(s[f][n][r]);
              pe[r] = (kg0 + r > qg) ? 0.f : e;
              rs[f] += pe[r];
            }
            p[f][n] = (bf16x4){(__bf16)pe[0], (__bf16)pe[1], (__bf16)pe[2], (__bf16)pe[3]};
          }
        }
      }

      __builtin_amdgcn_s_setprio(1);
#pragma unroll
      for (int m = 0; m < 4; ++m) {
        const int vrow = (m * 16 + l16) * 32;
#pragma unroll
        for (int n = 0; n < 4; ++n) {
          const int clog = (n & 1) * 2 + (quad >> 1);
          const int voff = vrow + (clog ^ rkey) * 8 + (quad & 1) * 4;
          bf16x4 va = *(const bf16x4*)&Vs[buf][n >> 1][voff];
#pragma unroll
          for (int f = 0; f < 2; ++f) o[f][m] = mfma16(va, p[f][n], o[f][m]);
        }
      }
      __builtin_amdgcn_s_setprio(0);
    }

#pragma unroll
    for (int f = 0; f < 2; ++f) {
      float t = rs[f];
      t += __shfl_xor(t, 16, 64);
      t += __shfl_xor(t, 32, 64);
      const float il = 1.f / t;
      const int q = qg0 + f * 16 + l16;
      ushort* dst = Ob + ((size_t)b * 2048 + q) * 1024 + h * 64;
#pragma unroll
      for (int m = 0; m < 4; ++m) {
        ushort4 w2;
        w2.x = f2bf(o[f][m][0] * il);
        w2.y = f2bf(o[f][m][1] * il);
        w2.z = f2bf(o[f][m][2] * il);
        w2.w = f2bf(o[f][m][3] * il);
        *(ushort4*)(dst + m * 16 + quad * 4) = w2;
      }
    }
  };

  process(15 - pair);
  __syncthreads();
  process(pair);
}

// ---------------- launch ----------------
extern "C" void kernel_launch(void* const* d_in, const int* in_sizes, int n_in,
                              void* d_out, int out_size, void* d_ws, size_t ws_size,
                              hipStream_t stream) {
  const float* x    = (const float*)d_in[0];  // [4,2048,1024]
  const float* Wqkv = (const float*)d_in[1];  // [1024,3072]
  const float* bqkv = (const float*)d_in[2];  // [3072]
  const float* Wo   = (const float*)d_in[3];  // [1024,1024]
  const float* bo   = (const float*)d_in[4];  // [1024]
  float* out = (float*)d_out;                 // [4,2048,1024] fp32

  char* ws = (char*)d_ws;
  size_t off = 0;
  auto alloc = [&](size_t bytes) {
    void* p = ws + off;
    off += (bytes + 255) & ~(size_t)255;
    return p;
  };
  ushort* Wqkv_t = (ushort*)alloc((size_t)3072 * 1024 * 2);
  ushort* Wo_t   = (ushort*)alloc((size_t)1024 * 1024 * 2);
  ushort* Qb     = (ushort*)alloc((size_t)64 * 2048 * 64 * 2);
  ushort* Kb     = (ushort*)alloc((size_t)64 * 2048 * 64 * 2);
  ushort* Vb     = (ushort*)alloc((size_t)64 * 2048 * 64 * 2);  // tiled V^T
  ushort* Ab     = (ushort*)alloc((size_t)8192 * 1024 * 2);

  // 1. fused weight transposes -> bf16 [N][K]
  prep_weights<<<dim3(128, 32), dim3(32, 8), 0, stream>>>(Wqkv, Wo, Wqkv_t, Wo_t);
  // 2. QKV projection: A = x (fp32) converted in-staging; scatter epilogue
  gemm_tb<0><<<dim3(24, 64), dim3(256), 0, stream>>>(nullptr, x, Wqkv_t, bqkv,
                                                     Qb, Kb, Vb, nullptr, 8192, 3072, 1024);
  // 3. causal flash attention (paired q-tiles; bh-per-XCD remap)
  attn_fused<<<dim3(8, 64), dim3(256), 0, stream>>>(Qb, Kb, Vb, Ab);
  // 4. output projection (pure-DMA path, fp32 out)
  gemm_tb<1><<<dim3(8, 64), dim3(256), 0, stream>>>(Ab, nullptr, Wo_t, bo,
                                                    nullptr, nullptr, nullptr, out,
                                                    8192, 1024, 1024);
}

// Round 7
// 253.204 us; speedup vs baseline: 1.0709x; 1.0709x over previous
//
#include <hip/hip_runtime.h>
#include <cstdint>
#include <cstddef>

typedef __bf16 bf16x8 __attribute__((ext_vector_type(8)));
typedef __bf16 bf16x4 __attribute__((ext_vector_type(4)));
typedef short s16x4 __attribute__((ext_vector_type(4)));
typedef float f32x4 __attribute__((ext_vector_type(4)));

__device__ __forceinline__ ushort f2bf(float f) {
  union { float f; uint32_t u; } v; v.f = f;
  uint32_t r = (v.u + 0x7fffu + ((v.u >> 16) & 1u)) >> 16;
  return (ushort)r;
}

__device__ __forceinline__ float fast_exp2(float x) {
#if defined(__HIP_DEVICE_COMPILE__) && __has_builtin(__builtin_amdgcn_exp2f)
  return __builtin_amdgcn_exp2f(x);
#else
  return exp2f(x);
#endif
}

// K=16 bf16 MFMA (C-layout of a 16x16 result feeds directly as B operand).
__device__ __forceinline__ f32x4 mfma16(bf16x4 a, bf16x4 b, f32x4 c) {
#if defined(__HIP_DEVICE_COMPILE__)
#if __has_builtin(__builtin_amdgcn_mfma_f32_16x16x16_bf16)
  return __builtin_amdgcn_mfma_f32_16x16x16_bf16(a, b, c, 0, 0, 0);
#else
  return __builtin_amdgcn_mfma_f32_16x16x16bf16_1k(
      __builtin_bit_cast(s16x4, a), __builtin_bit_cast(s16x4, b), c, 0, 0, 0);
#endif
#else
  (void)a; (void)b;
  return c;  // host stub, never executed
#endif
}

__device__ __forceinline__ void glds16(const ushort* g, ushort* l) {
  __builtin_amdgcn_global_load_lds((const __attribute__((address_space(1))) void*)g,
                                   (__attribute__((address_space(3))) void*)l, 16, 0, 0);
}

// ---------------- fp32 -> bf16 convert (vectorized) ----------------
__global__ void conv_bf16(const float4* __restrict__ in, ushort4* __restrict__ out, int n4) {
  int i = blockIdx.x * blockDim.x + threadIdx.x;
  if (i < n4) {
    float4 v = in[i];
    ushort4 o;
    o.x = f2bf(v.x); o.y = f2bf(v.y); o.z = f2bf(v.z); o.w = f2bf(v.w);
    out[i] = o;
  }
}

// ---------------- fused weight transposes: fp32 [R][C] -> bf16 [C][R] ----------------
// blockIdx.x < 96: Wqkv (1024x3072); else: Wo (1024x1024)
__global__ void prep_weights(const float* __restrict__ Wqkv, const float* __restrict__ Wo,
                             ushort* __restrict__ Wqkv_t, ushort* __restrict__ Wo_t) {
  __shared__ ushort t[32][33];
  const int bx = blockIdx.x;
  const float* in;
  ushort* out;
  int C, c0;
  if (bx < 96) { in = Wqkv; out = Wqkv_t; C = 3072; c0 = bx * 32; }
  else         { in = Wo;   out = Wo_t;   C = 1024; c0 = (bx - 96) * 32; }
  const int R = 1024;
  const int r0 = blockIdx.y * 32;
  const int tx = threadIdx.x, ty = threadIdx.y;  // 32 x 8
#pragma unroll
  for (int i = 0; i < 4; ++i)
    t[ty + i * 8][tx] = f2bf(in[(size_t)(r0 + ty + i * 8) * C + c0 + tx]);
  __syncthreads();
#pragma unroll
  for (int i = 0; i < 4; ++i)
    out[(size_t)(c0 + ty + i * 8) * R + r0 + tx] = t[tx][ty + i * 8];
}

// =====================================================================
// Triple-buffered bf16 GEMM (R4 structure, best measured: 84us QKV):
// 128x128 tile, BK=32, 4 waves of 64x64 (acc = 64 regs, spill-free at
// 3 waves/SIMD). LDS 48 KiB -> 3 blocks/CU. ONE raw barrier + counted
// s_waitcnt vmcnt(4) per K-step (stage(t+2) issued at t, waited end of
// t+1); slot-permuted LDS (conflict-free ds_read_b128, linear DMA dest,
// source-side permutation); setprio around the MFMA cluster; XCD remap.
// MODE 0: scatter epilogue to Q (scaled 0.125*log2e) / K / V^T tiled.
// MODE 1: fp32 direct out.
// =====================================================================
#define BAR8() do { asm volatile("" ::: "memory"); \
                    __builtin_amdgcn_s_barrier();  \
                    asm volatile("" ::: "memory"); } while (0)
#define VMC4()  asm volatile("s_waitcnt vmcnt(4)" ::: "memory")
#define VMC0()  asm volatile("s_waitcnt vmcnt(0)" ::: "memory")

template <int MODE>
__launch_bounds__(256, 3)
__global__ void gemm_tb(const ushort* __restrict__ A, const ushort* __restrict__ Bt,
                        const float* __restrict__ bias,
                        ushort* __restrict__ o0, ushort* __restrict__ o1,
                        ushort* __restrict__ o2, float* __restrict__ of,
                        int M, int N, int K) {
  __shared__ ushort smem[24576];  // 48 KiB: A bufs [0,12288), B bufs [12288,24576)
  const int NT = K >> 5;
  const int tid = threadIdx.x;
  const int wid = tid >> 6;
  const int lane = tid & 63;
  const int quad = lane >> 4;
  const int l16 = lane & 15;
  const int wm = (wid >> 1) * 64;
  const int wn = (wid & 1) * 64;

  // XCD-aware bijective remap (gridDim.x*gridDim.y % 8 == 0 in both modes)
  int wg = blockIdx.y * gridDim.x + blockIdx.x;
  const int ntx = gridDim.x;
  const int cpx = (ntx * gridDim.y) >> 3;
  wg = (wg & 7) * cpx + (wg >> 3);
  const int m0 = (wg / ntx) * 128;
  const int n0 = (wg % ntx) * 128;

  // ---- staging addressing (slot-permuted source, linear dest) ----
  const int r_l = lane >> 2;                      // row within 16-row sub-block
  const int q_l = ((lane & 3) - (r_l >> 1)) & 3;  // logical k-chunk this lane sources
  const ushort* gA0 = A + (size_t)(m0 + wid * 32 + r_l) * K + q_l * 8;
  const ushort* gB0 = Bt + (size_t)(n0 + wid * 32 + r_l) * K + q_l * 8;
  ushort* dA0 = smem + wid * 1024 + lane * 8;
  ushort* dB0 = smem + 12288 + wid * 1024 + lane * 8;

  auto stage = [&](int t, int bs) {   // 4 VMEM ops per thread
    const ushort* sa = gA0 + t * 32;
    ushort* da = dA0 + bs * 4096;
    glds16(sa, da);
    glds16(sa + 16 * K, da + 512);
    const ushort* sb = gB0 + t * 32;
    ushort* db = dB0 + bs * 4096;
    glds16(sb, db);
    glds16(sb + 16 * K, db + 512);
  };

  // ---- fragment read addressing ----
  const int slot8 = (l16 * 4 + ((quad + (l16 >> 1)) & 3)) * 8;
  const int abase = (wm >> 4) * 512 + slot8;            // + b*4096
  const int bbase = 12288 + (wn >> 4) * 512 + slot8;    // + b*4096

  f32x4 acc[4][4];
#pragma unroll
  for (int i = 0; i < 4; ++i)
#pragma unroll
    for (int j = 0; j < 4; ++j) acc[i][j] = (f32x4){0.f, 0.f, 0.f, 0.f};

  // ---- prologue: 2-deep prefetch ----
  stage(0, 0);
  stage(1, 1);
  VMC4();   // tile 0 landed; tile 1 (4 ops) may remain in flight
  BAR8();

  int b = 0;
  for (int t = 0; t < NT; ++t) {
    bf16x8 af[4], bfr[4];
    const int boff = b * 4096;
#pragma unroll
    for (int i = 0; i < 4; ++i)
      af[i] = *(const bf16x8*)(smem + boff + abase + i * 512);
#pragma unroll
    for (int j = 0; j < 4; ++j)
      bfr[j] = *(const bf16x8*)(smem + boff + bbase + j * 512);
    const int b2 = (b == 0) ? 2 : b - 1;    // (t+2) % 3
    if (t + 2 < NT) stage(t + 2, b2);       // overwrites buf read at t-1 (safe post-bar)
    __builtin_amdgcn_s_setprio(1);
#pragma unroll
    for (int i = 0; i < 4; ++i)
#pragma unroll
      for (int j = 0; j < 4; ++j)
        acc[i][j] = __builtin_amdgcn_mfma_f32_16x16x32_bf16(af[i], bfr[j], acc[i][j], 0, 0, 0);
    __builtin_amdgcn_s_setprio(0);
    // counted wait: buf for t+1 (staged at t-1) must be complete; the 4 ops
    // of stage(t+2) issued THIS iter may remain in flight.
    if (t + 2 < NT) { VMC4(); } else if (t + 1 < NT) { VMC0(); }
    BAR8();
    b = (b == 2) ? 0 : b + 1;
  }

  if (MODE == 1) {
#pragma unroll
    for (int i = 0; i < 4; ++i)
#pragma unroll
      for (int j = 0; j < 4; ++j) {
        const int col = n0 + wn + j * 16 + l16;
        const float bv = bias[col];
#pragma unroll
        for (int r = 0; r < 4; ++r) {
          const int row = m0 + wm + i * 16 + quad * 4 + r;
          of[(size_t)row * N + col] = acc[i][j][r] + bv;
        }
      }
  } else {
    // ---- scatter epilogue: 2 per-64-col-chunk passes, staged in LDS ----
    const int bb = m0 >> 11;
    const int s0 = m0 & 2047;
    const int wr = wid >> 1;     // row-half owner (R base = wr*64)
    const int wcol = wid & 1;    // col-half owner
#pragma unroll
    for (int hc = 0; hc < 2; ++hc) {
      const int gc0 = n0 + hc * 64;
      const int sel = gc0 >> 10;              // 0=Q 1=K 2=V (chunk head-aligned)
      const int head = (gc0 & 1023) >> 6;
      const size_t bh = (size_t)(bb * 16 + head);
      __syncthreads();                        // K-loop / prior pass reads done
      if (wcol == hc) {
#pragma unroll
        for (int j = 0; j < 4; ++j) {
          const int dloc = j * 16 + l16;      // 0..63
          const float bv = bias[gc0 + dloc];
#pragma unroll
          for (int i = 0; i < 4; ++i) {
#pragma unroll
            for (int r = 0; r < 4; ++r) {
              const int R = wr * 64 + i * 16 + quad * 4 + r;   // 0..127
              float v = acc[i][j][r] + bv;
              if (sel == 0) v *= 0.18033688011112042f;  // (1/8)*log2(e)
              const ushort u = f2bf(v);
              if (sel == 2) {
                const int lc = R >> 3;        // s-chunk 0..15
                smem[dloc * 128 + ((lc ^ (dloc & 7)) << 3) + (R & 7)] = u;
              } else {
                smem[R * 64 + (((dloc >> 3) ^ (R & 7)) << 3) + (dloc & 7)] = u;
              }
            }
          }
        }
      }
      __syncthreads();
      if (sel != 2) {
        ushort* o = sel ? o1 : o0;
        const int R = tid >> 1;               // 0..127
        const int gh = tid & 1;               // 64B half of the row
        ushort* dst = o + (bh * 2048 + s0 + R) * 64 + gh * 32;
        const int key = R & 7;
        const uint4* srow = (const uint4*)(smem + R * 64);
#pragma unroll
        for (int g = 0; g < 4; ++g)
          ((uint4*)dst)[g] = srow[(gh * 4 + g) ^ key];
      } else {
        const int d = tid >> 2;               // 0..63
        const int sq = tid & 3;               // 32-s quarter
        ushort* dst = o2 + (((size_t)(bh * 32 + (s0 >> 6) + (sq >> 1))) << 12) +
                      d * 64 + (sq & 1) * 32;
        const uint4* srow = (const uint4*)(smem + d * 128);
#pragma unroll
        for (int g = 0; g < 4; ++g)
          ((uint4*)dst)[g] = srow[(sq * 4 + g) ^ (d & 7)];
      }
    }
  }
}

// ---------------- flash attention (causal) ----------------
// Triple-buffered K/V staging with counted vmcnt (the R4 gemm medicine):
// raw barrier at loop top preceded by per-wave s_waitcnt vmcnt(4)
// (= stage(t) complete, stage(t+1) still in flight; vmcnt(0) only on the
// final iteration) -- the old __syncthreads() forced a vmcnt(0) drain of
// the prefetch DMA 34x/block. stage(t+2) issues right after the barrier
// (its dest buf was last read in iter t-1, ordered by this barrier).
// setprio around MFMA clusters; bh-per-XCD remap (8 bh x 512KB = one L2).
__launch_bounds__(256)
__global__ void attn_fused(const ushort* __restrict__ Qb, const ushort* __restrict__ Kb,
                           const ushort* __restrict__ Vt, ushort* __restrict__ Ob) {
  int wg0 = blockIdx.y * 8 + blockIdx.x;
  const int w = (wg0 & 7) * 64 + (wg0 >> 3);  // bijective over 512
  const int bh = w >> 3;           // b*16 + h
  const int pair = w & 7;          // 0..7
  const int tid = threadIdx.x;
  const int wid = tid >> 6;
  const int lane = tid & 63;
  const int quad = lane >> 4;
  const int l16 = lane & 15;

  __shared__ ushort Ks[3][2][64 * 32];  // [buf][half(d)][row=kv][32 d] (swizzled)
  __shared__ ushort Vs[3][2][64 * 32];  // [buf][half(kv)][row=d][32 kv] (swizzled)

  const int lr = lane >> 2;
  const int jphys = lane & 3;
  const int skey = (lr >> 1) & 3;
  const int jlog = jphys ^ skey;
  const int srow = wid * 16 + lr;
  const ushort* KgL = Kb + (size_t)bh * 2048 * 64 + (size_t)srow * 64 + jlog * 8;
  const ushort* VgL = Vt + (size_t)bh * 32 * 4096 + (size_t)srow * 64 + jlog * 8;
  ushort* ldsK0[3], *ldsK1[3], *ldsV0[3], *ldsV1[3];
#pragma unroll
  for (int buf = 0; buf < 3; ++buf) {
    ldsK0[buf] = &Ks[buf][0][wid * 16 * 32] + lane * 8;
    ldsK1[buf] = &Ks[buf][1][wid * 16 * 32] + lane * 8;
    ldsV0[buf] = &Vs[buf][0][wid * 16 * 32] + lane * 8;
    ldsV1[buf] = &Vs[buf][1][wid * 16 * 32] + lane * 8;
  }
  auto stage = [&](int jt, int buf) {   // 4 VMEM ops per thread
    const ushort* ks = KgL + (size_t)jt * 4096;
    const ushort* vs = VgL + (size_t)jt * 4096;
    glds16(ks, ldsK0[buf]);
    glds16(ks + 32, ldsK1[buf]);
    glds16(vs, ldsV0[buf]);
    glds16(vs + 32, ldsV1[buf]);
  };

  const int rkey = (l16 >> 1) & 3;
  const int b = bh >> 4, h = bh & 15;

  auto process = [&](int qt) {
    const int qg0 = qt * 128 + wid * 32;

    const ushort* Qg = Qb + ((size_t)bh * 2048 + qg0) * 64;
    bf16x8 qa[2][2];
#pragma unroll
    for (int f = 0; f < 2; ++f)
#pragma unroll
      for (int hh = 0; hh < 2; ++hh)
        qa[f][hh] = *(const bf16x8*)(Qg + (f * 16 + l16) * 64 + hh * 32 + quad * 8);

    f32x4 o[2][4];
    float rs[2];
#pragma unroll
    for (int f = 0; f < 2; ++f) {
      rs[f] = 0.f;
#pragma unroll
      for (int m = 0; m < 4; ++m) o[f][m] = (f32x4){0.f, 0.f, 0.f, 0.f};
    }

    const int nIt = 2 * qt + 2;  // block-uniform, >= 2
    stage(0, 0);
    stage(1, 1);

    int buf = 0;
    for (int jt = 0; jt < nIt; ++jt) {
      // counted wait: buf jt complete; stage(jt+1)'s 4 DMAs may stay in flight
      if (jt + 1 < nIt) { VMC4(); } else { VMC0(); }
      BAR8();
      const int b2 = (buf == 0) ? 2 : buf - 1;   // (jt+2) % 3
      if (jt + 2 < nIt) stage(jt + 2, b2);       // dest last read at jt-1 (pre-barrier)

      const int kvb = jt * 64;
      if (kvb <= qg0 + 31) {
        f32x4 s[2][4];
        __builtin_amdgcn_s_setprio(1);
#pragma unroll
        for (int n = 0; n < 4; ++n) {
          const int koff = (n * 16 + l16) * 32 + (quad ^ rkey) * 8;
          bf16x8 kb0 = *(const bf16x8*)&Ks[buf][0][koff];
          bf16x8 kb1 = *(const bf16x8*)&Ks[buf][1][koff];
#pragma unroll
          for (int f = 0; f < 2; ++f) {
            f32x4 z = (f32x4){0.f, 0.f, 0.f, 0.f};
            z = __builtin_amdgcn_mfma_f32_16x16x32_bf16(kb0, qa[f][0], z, 0, 0, 0);
            z = __builtin_amdgcn_mfma_f32_16x16x32_bf16(kb1, qa[f][1], z, 0, 0, 0);
            s[f][n] = z;
          }
        }
        __builtin_amdgcn_s_setprio(0);

        bf16x4 p[2][4];
        if (kvb + 63 <= qg0) {
#pragma unroll
          for (int f = 0; f < 2; ++f)
#pragma unroll
            for (int n = 0; n < 4; ++n) {
              float pe[4];
#pragma unroll
              for (int r = 0; r < 4; ++r) {
                pe[r] = fast_exp2(s[f][n][r]);
                rs[f] += pe[r];
              }
              p[f][n] = (bf16x4){(__bf16)pe[0], (__bf16)pe[1], (__bf16)pe[2], (__bf16)pe[3]};
            }
        } else {
#pragma unroll
          for (int f = 0; f < 2; ++f) {
            const int qg = qg0 + f * 16 + l16;
#pragma unroll
            for (int n = 0; n < 4; ++n) {
              const int kg0 = kvb + n * 16 + quad * 4;
              float pe[4];
#pragma unroll
              for (int r = 0; r < 4; ++r) {
                float e = fast_exp2(s[f][n][r]);
                pe[r] = (kg0 + r > qg) ? 0.f : e;
                rs[f] += pe[r];
              }
              p[f][n] = (bf16x4){(__bf16)pe[0], (__bf16)pe[1], (__bf16)pe[2], (__bf16)pe[3]};
            }
          }
        }

        __builtin_amdgcn_s_setprio(1);
#pragma unroll
        for (int m = 0; m < 4; ++m) {
          const int vrow = (m * 16 + l16) * 32;
#pragma unroll
          for (int n = 0; n < 4; ++n) {
            const int clog = (n & 1) * 2 + (quad >> 1);
            const int voff = vrow + (clog ^ rkey) * 8 + (quad & 1) * 4;
            bf16x4 va = *(const bf16x4*)&Vs[buf][n >> 1][voff];
#pragma unroll
            for (int f = 0; f < 2; ++f) o[f][m] = mfma16(va, p[f][n], o[f][m]);
          }
        }
        __builtin_amdgcn_s_setprio(0);
      }
      buf = (buf == 2) ? 0 : buf + 1;
    }

#pragma unroll
    for (int f = 0; f < 2; ++f) {
      float t = rs[f];
      t += __shfl_xor(t, 16, 64);
      t += __shfl_xor(t, 32, 64);
      const float il = 1.f / t;
      const int q = qg0 + f * 16 + l16;
      ushort* dst = Ob + ((size_t)b * 2048 + q) * 1024 + h * 64;
#pragma unroll
      for (int m = 0; m < 4; ++m) {
        ushort4 w2;
        w2.x = f2bf(o[f][m][0] * il);
        w2.y = f2bf(o[f][m][1] * il);
        w2.z = f2bf(o[f][m][2] * il);
        w2.w = f2bf(o[f][m][3] * il);
        *(ushort4*)(dst + m * 16 + quad * 4) = w2;
      }
    }
  };

  process(15 - pair);
  __syncthreads();     // all waves done with last tile before re-staging buf 0
  process(pair);
}

// ---------------- launch ----------------
extern "C" void kernel_launch(void* const* d_in, const int* in_sizes, int n_in,
                              void* d_out, int out_size, void* d_ws, size_t ws_size,
                              hipStream_t stream) {
  const float* x    = (const float*)d_in[0];  // [4,2048,1024]
  const float* Wqkv = (const float*)d_in[1];  // [1024,3072]
  const float* bqkv = (const float*)d_in[2];  // [3072]
  const float* Wo   = (const float*)d_in[3];  // [1024,1024]
  const float* bo   = (const float*)d_in[4];  // [1024]
  float* out = (float*)d_out;                 // [4,2048,1024] fp32

  char* ws = (char*)d_ws;
  size_t off = 0;
  auto alloc = [&](size_t bytes) {
    void* p = ws + off;
    off += (bytes + 255) & ~(size_t)255;
    return p;
  };
  ushort* xbf    = (ushort*)alloc((size_t)8192 * 1024 * 2);
  ushort* Wqkv_t = (ushort*)alloc((size_t)3072 * 1024 * 2);
  ushort* Wo_t   = (ushort*)alloc((size_t)1024 * 1024 * 2);
  ushort* Qb     = (ushort*)alloc((size_t)64 * 2048 * 64 * 2);
  ushort* Kb     = (ushort*)alloc((size_t)64 * 2048 * 64 * 2);
  ushort* Vb     = (ushort*)alloc((size_t)64 * 2048 * 64 * 2);  // tiled V^T
  ushort* Ab     = (ushort*)alloc((size_t)8192 * 1024 * 2);

  // 1. x -> bf16
  conv_bf16<<<dim3(8192), dim3(256), 0, stream>>>((const float4*)x, (ushort4*)xbf,
                                                  8192 * 1024 / 4);
  // 2. fused weight transposes -> bf16 [N][K]
  prep_weights<<<dim3(128, 32), dim3(32, 8), 0, stream>>>(Wqkv, Wo, Wqkv_t, Wo_t);
  // 3. QKV projection: triple-buffered counted-vmcnt GEMM, scatter epilogue
  gemm_tb<0><<<dim3(24, 64), dim3(256), 0, stream>>>(xbf, Wqkv_t, bqkv, Qb, Kb, Vb, nullptr,
                                                     8192, 3072, 1024);
  // 4. causal flash attention (triple-buffered, counted-vmcnt)
  attn_fused<<<dim3(8, 64), dim3(256), 0, stream>>>(Qb, Kb, Vb, Ab);
  // 5. output projection (same triple-buffered template, fp32 out)
  gemm_tb<1><<<dim3(8, 64), dim3(256), 0, stream>>>(Ab, Wo_t, bo, nullptr, nullptr, nullptr,
                                                    out, 8192, 1024, 1024);
}